// Round 1
// baseline (276.179 us; speedup 1.0000x reference)
//
#include <hip/hip_runtime.h>

// CfCHead: B=64, S=2048, H=1024 sequential nonlinear scan.
// Round-4: transcendental-pipe optimization.
//  - Per-step trans cut 10 -> 8.5 (all exact algebra):
//    * g/l sigmoids share ONE rcp: r = rcp((1+eg)*(1.01+el)); L2E folded
//      into Gi's exponent bias, sign applied via free VOP3 neg modifier.
//    * sigmoid(c) hoisted out of the serial loop (C-chain is independent of
//      h/sc) and batched with PAIRED rcps: rcp(A0*A1) serves two steps.
//      Safe: c>=0 always (c0=0, gates>0) => A in (1,2], product never
//      overflows.
//  - Software pipeline: gates for chunk k+1 (ILP-rich, 6 trans/step) are
//    computed in the same basic block as chunk k's serial m-chain, right
//    after it, so the scheduler fills the exp2(m) dependency bubbles.
//    Index clamp (t&2047) instead of a branch keeps ONE BB per chunk.
//    Il is produced in a second tiny pass (gates-B) so the h-chain can
//    read the old Il before the overwrite.
//  - Structure unchanged otherwise: 256 blocks x 512 threads, waves 0-3
//    producers (1 chain each), waves 4-7 projection consumers, one
//    barrier/chunk, double-buffered h in LDS (HSTR=17, conflict-free).

#define Bv   64
#define Sv   2048
#define Hv   1024
#define TPB  256      // producer (chain) threads per block
#define NT   512      // total threads per block
#define CH   16       // chunk (time steps per barrier)
#define HSTR 17       // LDS row stride (floats), odd -> conflict-free
#define HBUF (TPB * HSTR)

#define L2E   1.44269504088896340736f
#define NL2E (-1.44269504088896340736f)
#define LN2   0.69314718055994530942f
#define KNU   0.014426950408889634f     /* 0.01*L2E          */
#define CREB  0.692493619626702435f     /* 16*0.03*L2E       */
#define LOG2_001 (-6.6438561897747247f) /* log2(0.01)        */
#define LOG2_L2E 0.52876637294489777f   /* log2(L2E)         */

__device__ __forceinline__ float fexp2(float x) { return __builtin_amdgcn_exp2f(x); }
__device__ __forceinline__ float frcp(float x)  { return __builtin_amdgcn_rcpf(x); }

// out[b*S*2 + t*2 + k] = proj_b[k]  (clears 0xAA poison; scan atomically adds)
__global__ __launch_bounds__(256) void init_out(const float* __restrict__ proj_b,
                                                float* __restrict__ out) {
    int i = blockIdx.x * 256 + threadIdx.x;
    out[i] = proj_b[i & 1];
}

// gates-A: everything except Il; saves rA so Il can be finished later.
// trans: 5 exp2 + 1 rcp per step (was 5 exp2 + 2 rcp).
#define GATES_MAIN(tb)                                                \
    _Pragma("unroll")                                                 \
    for (int u = 0; u < CH; ++u) {                                    \
        const float xc = xrow[(tb) + u];                              \
        const float gi = fexp2(fmaf(xc, wi2, bi2));  /* L2E*e^pre_i */\
        const float gf = fexp2(fmaf(xc, wf2, bf2));  /* e^pre_f     */\
        const float go = fexp2(fmaf(xc, wo2, bo2));  /* .01*e^pre_o */\
        const float eg = fexp2(fmaf(xc, wg2, bg2));  /* e^-pre_g    */\
        const float el = fexp2(fmaf(xc, wl2, bl2));  /* e^-pre_l    */\
        const float Aq = 1.0f + eg;                                   \
        const float Bq = 1.01f + el;                                  \
        const float rq = frcp(Aq * Bq);      /* one rcp, two sigmoids */\
        gF[u]  = gf;                                                  \
        gOa[u] = go;                                                  \
        gIG[u] = gi * (rq * Bq);     /* L2E*e^pre_i*sig(pre_g), >0 */ \
        rA[u]  = rq * Aq;            /* 1/(1.01+el)                */ \
        gS[u]  = fmaf(go, 100.0f, fmaf(gi, LN2, gf)); /* e^i+e^f+e^o */\
    }

// gates-B: Il = 1 - 0.01/(1.01+el); runs AFTER h-chain consumed old Il.
#define GATES_IL()                                                    \
    _Pragma("unroll")                                                 \
    for (int u = 0; u < CH; ++u)                                      \
        gIl[u] = fmaf(rA[u], -0.01f, 1.0f);

__global__ __launch_bounds__(NT, 1) void cfc_scan(
    const float* __restrict__ x_codes,
    const float* __restrict__ Wi_w, const float* __restrict__ Wi_b,
    const float* __restrict__ Wf_w, const float* __restrict__ Wf_b,
    const float* __restrict__ Wo_w, const float* __restrict__ Wo_b,
    const float* __restrict__ Wg_w, const float* __restrict__ Wg_b,
    const float* __restrict__ Wl_w, const float* __restrict__ Wl_b,
    const float* __restrict__ proj_w,
    const float* __restrict__ n_init,
    float* __restrict__ out)
{
    __shared__ float hlds[2 * HBUF];    // double-buffered raw h, [par][j][u]
    __shared__ float pwlds[2 * TPB];    // proj_w staged, [k][j_local]

    const int b   = blockIdx.x >> 2;
    const int q   = blockIdx.x & 3;
    const int tid = threadIdx.x;

    const float* __restrict__ xrow = x_codes + b * Sv;
    float* __restrict__ orow = out + b * (Sv * 2);

    // ---- consumer setup (waves 4-7) ----
    const int ct   = tid - TPB;
    const int rk   = (ct >> 7) & 1;
    const int rt   = (ct >> 3) & 15;
    const int rseg = ct & 7;
    if (tid >= TPB) {
        pwlds[ct]       = proj_w[q * TPB + ct];
        pwlds[TPB + ct] = proj_w[Hv + q * TPB + ct];
    }

    // ---- producer setup (waves 0-3): fold all affine maps into weights ----
    float wi2 = 0, bi2 = 0, wf2 = 0, bf2 = 0, wo2 = 0, bo2 = 0;
    float wg2 = 0, bg2 = 0, wl2 = 0, bl2 = 0;
    float m = 0, En = 0, C = 0, h = 0;
    if (tid < TPB) {
        const int j = q * TPB + tid;
        const float wi = Wi_w[j], bi = Wi_b[j];
        const float wf = Wf_w[j], bf = Wf_b[j];
        const float wo = Wo_w[j], bo = Wo_b[j];
        const float wg = Wg_w[j], bg = Wg_b[j];
        const float wl = Wl_w[j], bl = Wl_b[j];
        // pre = ((code-65)/100)*w + b ; exponent_arg = pre*L2E = code*w' + b'
        // Gi carries an extra L2E factor (bias += log2(L2E)) so that
        // GiGg = L2E*e^{pre_i}*sig_g directly; sign applied at the fma.
        wi2 = wi * KNU;  bi2 = fmaf(-0.65f, wi, bi) * L2E + LOG2_L2E;
        wf2 = wf * KNU;  bf2 = fmaf(-0.65f, wf, bf) * L2E;
        wo2 = wo * KNU;  bo2 = fmaf(-0.65f, wo, bo) * L2E + LOG2_001; // 0.01*e^pre_o
        wg2 = -wg * KNU; bg2 = fmaf(-0.65f, wg, bg) * NL2E;           // for e^{-pre_g}
        wl2 = -wl * KNU; bl2 = fmaf(-0.65f, wl, bl) * NL2E;
        m  = n_init[j] * NL2E;   // m = -n*L2E (drift-free form)
        En = fexp2(m);           // e^{-n}
    }

    float gF[CH], gIG[CH], gOa[CH], gS[CH], gIl[CH], rA[CH];
    float Carr[CH], Pa[CH];

    // 2^{0.03*L2E*u} = e^{0.03u}: per-step drift of e^{-n}, compile-time
    static const float CUP[CH] = {
        1.0f,        1.03045453f, 1.06183655f, 1.09417428f,
        1.12749685f, 1.16183424f, 1.19721736f, 1.23367806f,
        1.27124915f, 1.30996445f, 1.34985881f, 1.39096813f,
        1.43332941f, 1.47698079f, 1.52196156f, 1.56831219f };

    if (tid < TPB) {
        GATES_MAIN(0)
        GATES_IL()
    }

    int par = 0;
    for (int t0 = 0; t0 < Sv; t0 += CH, par ^= 1) {
        if (tid < TPB) {
            // -- serial m/C chain: only exp2(m) is transcendental --
            #pragma unroll
            for (int u = 0; u < CH; ++u) {
                const float Enu = (u == 0) ? En : En * CUP[u];   // e^{-n_t}
                const float ef  = gF[u] * Enu;                   // f_t
                C = fmaf(ef, C, -(gIG[u] * Enu));                // C = -L2E*c
                Carr[u] = C;
                Pa[u]   = gOa[u] * Enu;                          // 0.01*o_t
                m = fmaf(gS[u] * Enu, -KNU, m);
                if (u == CH - 1) m += CREB;                      // drift rebase
                En = fexp2(m);
            }
            // -- gates for NEXT chunk: trans-dense, independent work that
            //    the scheduler interleaves with the m-chain's stalls.
            //    (&(Sv-1): last chunk harmlessly recomputes t=0 gates.) --
            const int tnext = (t0 + CH) & (Sv - 1);
            GATES_MAIN(tnext)
            // -- batched sigmoid(c): paired rcps; then the short h chain --
            float* __restrict__ hrow = &hlds[par * HBUF + tid * HSTR];
            #pragma unroll
            for (int u = 0; u < CH; u += 2) {
                const float A0 = 1.0f + fexp2(Carr[u]);      // 1+e^{-c}, (1,2]
                const float A1 = 1.0f + fexp2(Carr[u + 1]);
                const float rr = frcp(A0 * A1);              // one rcp, 2 steps
                h = fmaf(Pa[u],     rr * A1, h) * gIl[u];
                hrow[u] = h;
                h = fmaf(Pa[u + 1], rr * A0, h) * gIl[u + 1];
                hrow[u + 1] = h;
            }
            GATES_IL()      // overwrite Il only after h-chain consumed it
        }
        __syncthreads();   // producers publish h[par]; consumers sync to it
        if (tid >= TPB) {
            const float* __restrict__ hb  = &hlds[par * HBUF];
            const float* __restrict__ pwk = &pwlds[rk * TPB];
            float sum = 0.0f;
            #pragma unroll
            for (int i2 = 0; i2 < 32; ++i2) {
                const int v  = (i2 + 4 * rseg) & 31;   // rotation: 2-way banks
                const int jj = rseg * 32 + v;
                sum = fmaf(hb[jj * HSTR + rt], pwk[jj], sum);  // pw read = broadcast
            }
            sum += __shfl_xor(sum, 1, 64);
            sum += __shfl_xor(sum, 2, 64);
            sum += __shfl_xor(sum, 4, 64);
            if (rseg == 0) atomicAdd(&orow[(t0 + rt) * 2 + rk], sum);
        }
    }
}

extern "C" void kernel_launch(void* const* d_in, const int* in_sizes, int n_in,
                              void* d_out, int out_size, void* d_ws, size_t ws_size,
                              hipStream_t stream) {
    const float* x_codes = (const float*)d_in[0];
    const float* Wi_w = (const float*)d_in[1];
    const float* Wi_b = (const float*)d_in[2];
    const float* Wf_w = (const float*)d_in[3];
    const float* Wf_b = (const float*)d_in[4];
    const float* Wo_w = (const float*)d_in[5];
    const float* Wo_b = (const float*)d_in[6];
    const float* Wg_w = (const float*)d_in[7];
    const float* Wg_b = (const float*)d_in[8];
    const float* Wl_w = (const float*)d_in[9];
    const float* Wl_b = (const float*)d_in[10];
    const float* proj_w = (const float*)d_in[11];
    const float* proj_b = (const float*)d_in[12];
    const float* n_init = (const float*)d_in[13];
    float* out = (float*)d_out;

    init_out<<<out_size / 256, 256, 0, stream>>>(proj_b, out);
    cfc_scan<<<Bv * (Hv / TPB), NT, 0, stream>>>(
        x_codes, Wi_w, Wi_b, Wf_w, Wf_b, Wo_w, Wo_b, Wg_w, Wg_b, Wl_w, Wl_b,
        proj_w, n_init, out);
}